// Round 2
// baseline (628.368 us; speedup 1.0000x reference)
//
#include <hip/hip_runtime.h>

// Problem constants (match reference)
#define NUM_CHIPS 8
#define EPC 8
#define E_EXPERTS 64
#define TOPK 4
#define META 8
#define M_CAP 1024
#define SEQ 512
#define HID 2048
#define SK (SEQ * TOPK)          // 2048 dispatch entries per chip
#define ROWS (E_EXPERTS * M_CAP) // 65536 output rows

// d_out layout (flat float32):
//   dispatched : [0, ROWS*HID)
//   metadata   : [ROWS*HID, ROWS*HID + ROWS*META)
//   tokens     : [ROWS*HID + ROWS*META, +64)
#define DISP_SZ ((size_t)ROWS * HID)           // 134217728
#define META_OFF DISP_SZ
#define TOK_OFF (DISP_SZ + (size_t)ROWS * META)

// d_ws layout (ints)
#define WS_INV 0                    // inv_map[65536]: entry id per used slot
#define WS_CNT (ROWS)               // counts[8][64]
#define WS_OFB (ROWS + 512)         // offset_base[8][64]
#define WS_TOT (ROWS + 1024)        // total[64]

typedef float vfloat4 __attribute__((ext_vector_type(4)));

// ---------------------------------------------------------------------------
// Kernel 1: per-chip expert histogram. [unchanged, verified]
// ---------------------------------------------------------------------------
__global__ __launch_bounds__(256) void count_kernel(const int* __restrict__ idx,
                                                    int* __restrict__ ws) {
    const int c = blockIdx.x;
    const int t = threadIdx.x;
    __shared__ __align__(16) unsigned char f[SK];
    __shared__ int partial[4][E_EXPERTS];

    const int* ic = idx + c * SK;
    for (int i = t; i < SK; i += 256) f[i] = (unsigned char)ic[i];
    __syncthreads();

    const int e = t & 63;
    const int q = t >> 6;
    const unsigned eb = (unsigned)e;
    const unsigned* fw = (const unsigned*)f;
    int cnt = 0;
    for (int w = q * 128; w < q * 128 + 128; ++w) {
        unsigned v = fw[w];
        cnt += ((v & 0xffu) == eb);
        cnt += (((v >> 8) & 0xffu) == eb);
        cnt += (((v >> 16) & 0xffu) == eb);
        cnt += ((v >> 24) == eb);
    }
    partial[q][e] = cnt;
    __syncthreads();
    if (q == 0) {
        int s = partial[0][e] + partial[1][e] + partial[2][e] + partial[3][e];
        ws[WS_CNT + c * E_EXPERTS + e] = s;
    }
}

// ---------------------------------------------------------------------------
// Kernel 2: exclusive prefix over chips. [unchanged]
// ---------------------------------------------------------------------------
__global__ void prefix_kernel(int* __restrict__ ws, float* __restrict__ out) {
    const int e = threadIdx.x;  // 0..63
    int base = 0;
    for (int c = 0; c < NUM_CHIPS; ++c) {
        ws[WS_OFB + c * E_EXPERTS + e] = base;
        base += ws[WS_CNT + c * E_EXPERTS + e];
    }
    ws[WS_TOT + e] = base;
    out[TOK_OFF + e] = (float)base;
}

// ---------------------------------------------------------------------------
// Kernel 3: per-entry rank + inv_map scatter. [unchanged, verified]
// ---------------------------------------------------------------------------
__global__ __launch_bounds__(256) void rank_kernel(const int* __restrict__ idx,
                                                   int* __restrict__ ws) {
    const int c = blockIdx.x;
    const int t = threadIdx.x;
    __shared__ __align__(16) unsigned char f[SK];
    __shared__ int partial[4][E_EXPERTS];

    const int* ic = idx + c * SK;
    for (int i = t; i < SK; i += 256) f[i] = (unsigned char)ic[i];
    __syncthreads();

    const int e = t & 63;
    const int q = t >> 6;
    const unsigned eb = (unsigned)e;
    const unsigned* fw = (const unsigned*)f;
    int cnt = 0;
    for (int w = q * 128; w < q * 128 + 128; ++w) {
        unsigned v = fw[w];
        cnt += ((v & 0xffu) == eb);
        cnt += (((v >> 8) & 0xffu) == eb);
        cnt += (((v >> 16) & 0xffu) == eb);
        cnt += ((v >> 24) == eb);
    }
    partial[q][e] = cnt;
    __syncthreads();

    int base = ws[WS_OFB + c * E_EXPERTS + e];
    for (int qq = 0; qq < q; ++qq) base += partial[qq][e];

    int* inv = ws + WS_INV;
    for (int i = q * 512; i < q * 512 + 512; ++i) {
        if ((int)f[i] == e) {
            inv[e * M_CAP + base] = c * SK + i;  // entry id
            ++base;
        }
    }
}

// ---------------------------------------------------------------------------
// Kernel 4: the 512 MB writer.
// v3: IDENTICAL structure to v2 (16 rows/block, 2-stage pipeline) but with
// PLAIN stores instead of __builtin_nontemporal_store.
// Rationale (single-variable A/B): v1 and v2 both landed at ~260 µs with nt
// stores (~2.0 TB/s effective), while the harness's fillBufferAligned proves
// plain dwordx4 stores sustain 6.3 TB/s on this same buffer. No write reuse
// exists to protect, and x (32 MiB) stays L2/L3-resident regardless.
// ---------------------------------------------------------------------------
#define RPB 16                       // rows per block; divides M_CAP
#define FILL_GRID (ROWS / RPB)       // 4096 blocks

__global__ __launch_bounds__(256) void fill_kernel(const float* __restrict__ x,
                                                   const float* __restrict__ wts,
                                                   const int* __restrict__ ws,
                                                   float* __restrict__ out) {
    const int t = threadIdx.x;
    const int base_row = blockIdx.x * RPB;
    const int e = base_row >> 10;            // expert (uniform per block)
    const int p0 = base_row & (M_CAP - 1);   // first position in expert buffer

    const int total = ws[WS_TOT + e];
    int nused = total - p0;
    if (nused < 0) nused = 0;
    if (nused > RPB) nused = RPB;

    // ---------------- used rows: pipelined gather-copy ----------------
    if (nused > 0) {
        int entry = ws[WS_INV + base_row];
        const vfloat4* s4 = (const vfloat4*)(x + (size_t)(entry >> 2) * HID);
        vfloat4 v0 = s4[t];
        vfloat4 v1 = s4[t + 256];

        for (int r = 0; r < nused; ++r) {
            const int cur = entry;
            vfloat4 w0 = v0;
            vfloat4 w1 = v1;
            if (r + 1 < nused) {                 // prefetch next row
                entry = ws[WS_INV + base_row + r + 1];
                const vfloat4* n4 = (const vfloat4*)(x + (size_t)(entry >> 2) * HID);
                v0 = n4[t];
                v1 = n4[t + 256];
            }
            vfloat4* d4 = (vfloat4*)(out + (size_t)(base_row + r) * HID);
            d4[t] = w0;
            d4[t + 256] = w1;

            if (t < META) {
                float mv;
                if (t == 0)      mv = (float)(cur >> 11);              // chip
                else if (t == 1) mv = (float)((cur >> 2) & (SEQ - 1)); // token
                else if (t == 2) mv = (float)(cur & 3);                // k
                else if (t == 3) mv = (float)e;                        // expert
                else if (t == 4) mv = (float)((int)wts[cur]);          // int(weight)
                else             mv = 0.0f;
                out[META_OFF + (size_t)(base_row + r) * META + t] = mv;
            }
        }
    }

    // ---------------- unused rows: zero burst ----------------
    const vfloat4 z = (vfloat4)(0.0f);
    for (int r = nused; r < RPB; ++r) {
        vfloat4* d4 = (vfloat4*)(out + (size_t)(base_row + r) * HID);
        d4[t] = z;
        d4[t + 256] = z;
        if (t < META) out[META_OFF + (size_t)(base_row + r) * META + t] = -1.0f;
    }
}

// ---------------------------------------------------------------------------
extern "C" void kernel_launch(void* const* d_in, const int* in_sizes, int n_in,
                              void* d_out, int out_size, void* d_ws, size_t ws_size,
                              hipStream_t stream) {
    const float* x   = (const float*)d_in[0];   // (8,512,2048) f32
    const float* wts = (const float*)d_in[1];   // (8,512,4) f32
    const int* idx   = (const int*)d_in[2];     // (8,512,4) i32
    float* out = (float*)d_out;
    int* ws = (int*)d_ws;

    count_kernel<<<NUM_CHIPS, 256, 0, stream>>>(idx, ws);
    prefix_kernel<<<1, 64, 0, stream>>>(ws, out);
    rank_kernel<<<NUM_CHIPS, 256, 0, stream>>>(idx, ws);
    fill_kernel<<<FILL_GRID, 256, 0, stream>>>(x, wts, ws, out);
}

// Round 4
// 615.530 us; speedup vs baseline: 1.0209x; 1.0209x over previous
//
#include <hip/hip_runtime.h>

// Problem constants (match reference)
#define NUM_CHIPS 8
#define EPC 8
#define E_EXPERTS 64
#define TOPK 4
#define META 8
#define M_CAP 1024
#define SEQ 512
#define HID 2048
#define SK (SEQ * TOPK)          // 2048 dispatch entries per chip
#define NENT (NUM_CHIPS * SK)    // 16384 total dispatch entries (== used rows)
#define ROWS (E_EXPERTS * M_CAP) // 65536 output rows

// d_out layout (flat float32):
//   dispatched : [0, ROWS*HID)
//   metadata   : [ROWS*HID, ROWS*HID + ROWS*META)
//   tokens     : [ROWS*HID + ROWS*META, +64)
#define DISP_SZ ((size_t)ROWS * HID)           // 134217728 floats
#define META_OFF DISP_SZ
#define TOK_OFF (DISP_SZ + (size_t)ROWS * META)

// d_ws layout (ints)
#define WS_INV 0                     // inv_map[65536]: entry id per used slot
#define WS_CNT 65536                 // counts[8][64]
#define WS_OFB 66048                 // offset_base[8][64]
#define WS_TOT 66560                 // total[64]
#define WS_GB 66624                  // global_base[64]: excl. prefix of totals
#define WS_DENT 66688                // dense entry id [16384]
#define WS_DROW 83072                // dense output row [16384]
// total ws use: 99456 ints = 389 KB

typedef float vfloat4 __attribute__((ext_vector_type(4)));

// ---------------------------------------------------------------------------
// Kernel 1: per-chip expert histogram. [unchanged, verified]
// ---------------------------------------------------------------------------
__global__ __launch_bounds__(256) void count_kernel(const int* __restrict__ idx,
                                                    int* __restrict__ ws) {
    const int c = blockIdx.x;
    const int t = threadIdx.x;
    __shared__ __align__(16) unsigned char f[SK];
    __shared__ int partial[4][E_EXPERTS];

    const int* ic = idx + c * SK;
    for (int i = t; i < SK; i += 256) f[i] = (unsigned char)ic[i];
    __syncthreads();

    const int e = t & 63;
    const int q = t >> 6;
    const unsigned eb = (unsigned)e;
    const unsigned* fw = (const unsigned*)f;
    int cnt = 0;
    for (int w = q * 128; w < q * 128 + 128; ++w) {
        unsigned v = fw[w];
        cnt += ((v & 0xffu) == eb);
        cnt += (((v >> 8) & 0xffu) == eb);
        cnt += (((v >> 16) & 0xffu) == eb);
        cnt += ((v >> 24) == eb);
    }
    partial[q][e] = cnt;
    __syncthreads();
    if (q == 0) {
        int s = partial[0][e] + partial[1][e] + partial[2][e] + partial[3][e];
        ws[WS_CNT + c * E_EXPERTS + e] = s;
    }
}

// ---------------------------------------------------------------------------
// Kernel 2: exclusive prefix over chips -> offset_base, totals, tokens out.
// Also exclusive prefix of totals over experts -> global_base.
// ---------------------------------------------------------------------------
__global__ void prefix_kernel(int* __restrict__ ws, float* __restrict__ out) {
    const int e = threadIdx.x;  // 0..63
    int base = 0;
    for (int c = 0; c < NUM_CHIPS; ++c) {
        ws[WS_OFB + c * E_EXPERTS + e] = base;
        base += ws[WS_CNT + c * E_EXPERTS + e];
    }
    ws[WS_TOT + e] = base;
    out[TOK_OFF + e] = (float)base;

    __shared__ int tot[E_EXPERTS];
    tot[e] = base;
    __syncthreads();
    if (e == 0) {
        int g = 0;
        for (int i = 0; i < E_EXPERTS; ++i) { ws[WS_GB + i] = g; g += tot[i]; }
    }
}

// ---------------------------------------------------------------------------
// Kernel 3: per-entry rank; scatter entry ids into inv_map AND the dense
// used-slot list (dense idx = global_base[e] + within-expert slot).
// ---------------------------------------------------------------------------
__global__ __launch_bounds__(256) void rank_kernel(const int* __restrict__ idx,
                                                   int* __restrict__ ws) {
    const int c = blockIdx.x;
    const int t = threadIdx.x;
    __shared__ __align__(16) unsigned char f[SK];
    __shared__ int partial[4][E_EXPERTS];

    const int* ic = idx + c * SK;
    for (int i = t; i < SK; i += 256) f[i] = (unsigned char)ic[i];
    __syncthreads();

    const int e = t & 63;
    const int q = t >> 6;
    const unsigned eb = (unsigned)e;
    const unsigned* fw = (const unsigned*)f;
    int cnt = 0;
    for (int w = q * 128; w < q * 128 + 128; ++w) {
        unsigned v = fw[w];
        cnt += ((v & 0xffu) == eb);
        cnt += (((v >> 8) & 0xffu) == eb);
        cnt += (((v >> 16) & 0xffu) == eb);
        cnt += ((v >> 24) == eb);
    }
    partial[q][e] = cnt;
    __syncthreads();

    int base = ws[WS_OFB + c * E_EXPERTS + e];
    for (int qq = 0; qq < q; ++qq) base += partial[qq][e];
    const int gb = ws[WS_GB + e];

    for (int i = q * 512; i < q * 512 + 512; ++i) {
        if ((int)f[i] == e) {
            const int entry = c * SK + i;
            ws[WS_INV + e * M_CAP + base] = entry;
            ws[WS_DENT + gb + base] = entry;
            ws[WS_DROW + gb + base] = e * M_CAP + base;
            ++base;
        }
    }
}

// ---------------------------------------------------------------------------
// Kernel 4 (replaces Round-3's hipMemsetAsync — no runtime API inside
// kernel_launch): zero ONLY the unused tail rows (p >= total[e]), ~384 MB.
// 16 consecutive rows per block (same expert), pure streaming dwordx4
// stores, no dependencies -> should run at memset-class BW.
// ---------------------------------------------------------------------------
#define ZRPB 16
#define ZERO_GRID (ROWS / ZRPB)      // 4096 blocks

__global__ __launch_bounds__(256) void zero_tail(const int* __restrict__ ws,
                                                 float* __restrict__ out) {
    const int t = threadIdx.x;
    const int base_row = blockIdx.x * ZRPB;
    const int e = base_row >> 10;
    const int p0 = base_row & (M_CAP - 1);

    const int total = ws[WS_TOT + e];
    int nused = total - p0;              // rows [0, nused) are used
    if (nused < 0) nused = 0;
    if (nused > ZRPB) nused = ZRPB;

    const vfloat4 z = (vfloat4)(0.0f);
    for (int r = nused; r < ZRPB; ++r) {
        vfloat4* d4 = (vfloat4*)(out + (size_t)(base_row + r) * HID);
        d4[t] = z;
        d4[t + 256] = z;
    }
}

// ---------------------------------------------------------------------------
// Kernel 5: metadata for ALL rows. 32 rows/block, 8 lanes/row. 2 MB total.
// ---------------------------------------------------------------------------
__global__ __launch_bounds__(256) void meta_kernel(const float* __restrict__ wts,
                                                   const int* __restrict__ ws,
                                                   float* __restrict__ out) {
    const int t = threadIdx.x;
    const int row = blockIdx.x * 32 + (t >> 3);
    const int j = t & 7;
    const int e = row >> 10;
    const int p = row & (M_CAP - 1);

    float mv = -1.0f;
    if (p < ws[WS_TOT + e]) {
        const int entry = ws[WS_INV + row];
        if (j == 0)      mv = (float)(entry >> 11);                // chip
        else if (j == 1) mv = (float)((entry >> 2) & (SEQ - 1));   // token
        else if (j == 2) mv = (float)(entry & 3);                  // k
        else if (j == 3) mv = (float)e;                            // expert
        else if (j == 4) mv = (float)((int)wts[entry]);            // int(weight)
        else             mv = 0.0f;
    }
    out[META_OFF + (size_t)row * META + j] = mv;
}

// ---------------------------------------------------------------------------
// Kernel 6: copy the 16384 USED rows only (128 MB W + ~134 MB R, x is
// L2/L3-resident). 8 rows/block, entries staged in LDS so every x load is
// independent; full unroll -> up to 16 gathered dwordx4 loads in flight.
// ---------------------------------------------------------------------------
#define RPU 8
#define USED_GRID (NENT / RPU)   // 2048 blocks

__global__ __launch_bounds__(256) void fill_used(const float* __restrict__ x,
                                                 const int* __restrict__ ws,
                                                 float* __restrict__ out) {
    const int t = threadIdx.x;
    const int g0 = blockIdx.x * RPU;

    __shared__ int sh_ent[RPU];
    __shared__ int sh_row[RPU];
    if (t < RPU)           sh_ent[t] = ws[WS_DENT + g0 + t];
    else if (t < 2 * RPU)  sh_row[t - RPU] = ws[WS_DROW + g0 + (t - RPU)];
    __syncthreads();

#pragma unroll
    for (int r = 0; r < RPU; ++r) {
        const vfloat4* s4 = (const vfloat4*)(x + (size_t)(sh_ent[r] >> 2) * HID);
        vfloat4* d4 = (vfloat4*)(out + (size_t)sh_row[r] * HID);
        vfloat4 v0 = s4[t];
        vfloat4 v1 = s4[t + 256];
        d4[t] = v0;
        d4[t + 256] = v1;
    }
}

// ---------------------------------------------------------------------------
extern "C" void kernel_launch(void* const* d_in, const int* in_sizes, int n_in,
                              void* d_out, int out_size, void* d_ws, size_t ws_size,
                              hipStream_t stream) {
    const float* x   = (const float*)d_in[0];   // (8,512,2048) f32
    const float* wts = (const float*)d_in[1];   // (8,512,4) f32
    const int* idx   = (const int*)d_in[2];     // (8,512,4) i32
    float* out = (float*)d_out;
    int* ws = (int*)d_ws;

    count_kernel<<<NUM_CHIPS, 256, 0, stream>>>(idx, ws);
    prefix_kernel<<<1, 64, 0, stream>>>(ws, out);
    rank_kernel<<<NUM_CHIPS, 256, 0, stream>>>(idx, ws);
    zero_tail<<<ZERO_GRID, 256, 0, stream>>>(ws, out);
    meta_kernel<<<ROWS / 32, 256, 0, stream>>>(wts, ws, out);
    fill_used<<<USED_GRID, 256, 0, stream>>>(x, ws, out);
}